// Round 5
// baseline (19932.037 us; speedup 1.0000x reference)
//
#include <hip/hip_runtime.h>

#define SEQ 256
#define BS 64
#define INF 512
#define HID 1024
#define KEXP 4
#define G4 4096          // 4*HID

typedef __attribute__((ext_vector_type(8))) short s16x8;
typedef __attribute__((ext_vector_type(4))) float f32x4;

__device__ __forceinline__ short f2bf(float x) {
  unsigned u = __builtin_bit_cast(unsigned, x);
  u += 0x7fffu + ((u >> 16) & 1u);
  return (short)(u >> 16);
}

__device__ __forceinline__ float sigf(float x) {
  return 1.f / (1.f + __expf(-x));
}
__device__ __forceinline__ float tanhfast(float x) {
  return 2.f / (1.f + __expf(-2.f * x)) - 1.f;
}

__global__ void cvt_kernel(const float* __restrict__ s, short* __restrict__ d, int n4) {
  int stride = gridDim.x * blockDim.x;
  for (int i = blockIdx.x * blockDim.x + threadIdx.x; i < n4; i += stride) {
    float4 v = reinterpret_cast<const float4*>(s)[i];
    short4 o = make_short4(f2bf(v.x), f2bf(v.y), f2bf(v.z), f2bf(v.w));
    reinterpret_cast<short4*>(d)[i] = o;
  }
}

__global__ void prep_misc(const float* __restrict__ h0, const float* __restrict__ coef,
                          short* __restrict__ hbuf0, float* __restrict__ wtsbuf,
                          unsigned* __restrict__ bar) {
  int i = blockIdx.x * blockDim.x + threadIdx.x;   // 65536 threads == BS*HID
  hbuf0[i] = f2bf(h0[i]);
  if (i < 1024) bar[i] = 0u;
  if (i < SEQ) {
    float a = coef[i*4+0], b = coef[i*4+1], c = coef[i*4+2], d = coef[i*4+3];
    float m = fmaxf(fmaxf(a, b), fmaxf(c, d));
    float ea = __expf(a-m), eb = __expf(b-m), ec = __expf(c-m), ed = __expf(d-m);
    float inv = 1.f / (ea+eb+ec+ed);
    wtsbuf[i*4+0]=ea*inv; wtsbuf[i*4+1]=eb*inv; wtsbuf[i*4+2]=ec*inv; wtsbuf[i*4+3]=ed*inv;
  }
}

// Persistent kernel: 256 WGs x 512 threads, 1 WG/CU (146KB LDS forces it).
// WG wg owns h-cols [wg*4, wg*4+4) => 64 GEMM N-cols (4 experts x 4 gates x 4 j),
// n = e*16 + gate*4 + j. Wave w (0..7) owns k-slice [w*192, w*192+192) of the
// concatenated [h(1024)|x(512)] K-dim, with B (weights) in VGPRs (24 frags).
// Per step: A=[h|x_t] staged to LDS in 3x512-col phases (double-buffered,
// XOR-swizzled source), MFMA partials per wave, 8-phase LDS reduction,
// WG-local LSTM cell + mixture (c in regs), grid barrier via device atomics.
#define PHASE(c, bufofs)                                                         \
  { _Pragma("unroll")                                                            \
    for (int i = 0; i < 6; ++i) {                                                \
      if (((kk0 + i) >> 4) == (c)) {                                             \
        const int kbyte = ((kk0 + i - (c) * 16) << 6) + ((lane >> 4) << 4);      \
        _Pragma("unroll")                                                        \
        for (int m = 0; m < 4; ++m) {                                            \
          const int rowA = m * 16 + n16;                                         \
          const int addr = rowA * 1024 + (kbyte ^ ((rowA & 7) << 4));            \
          s16x8 af = *reinterpret_cast<const s16x8*>(sA + (bufofs) + (addr >> 1)); \
          acc[m][0] = __builtin_amdgcn_mfma_f32_16x16x32_bf16(af, wr[0][i], acc[m][0], 0, 0, 0); \
          acc[m][1] = __builtin_amdgcn_mfma_f32_16x16x32_bf16(af, wr[1][i], acc[m][1], 0, 0, 0); \
          acc[m][2] = __builtin_amdgcn_mfma_f32_16x16x32_bf16(af, wr[2][i], acc[m][2], 0, 0, 0); \
          acc[m][3] = __builtin_amdgcn_mfma_f32_16x16x32_bf16(af, wr[3][i], acc[m][3], 0, 0, 0); \
        }                                                                        \
      }                                                                          \
    }                                                                            \
  }

__global__ __launch_bounds__(512, 2) void moo_persistent(
    const float* __restrict__ Wih,   // [K][4096][512] f32
    const float* __restrict__ Whh,   // [K][4096][1024] f32
    const float* __restrict__ bih,   // [K][4096]
    const float* __restrict__ bhh,   // [K][4096]
    const float* __restrict__ c0,    // [64][1024]
    const short* __restrict__ xb,    // [SEQ][64][512] bf16
    const float* __restrict__ wtsbuf,// [SEQ][4]
    short* __restrict__ hbuf,        // [2][64][1024] bf16
    unsigned* __restrict__ bar,      // [64*16]
    float* __restrict__ outf)        // d_out
{
  __shared__ short sA[65536];        // 2 x [64 rows][512 k] bf16 = 128 KB
  __shared__ float sG[64 * 68];      // col-major gate grid [n][row-padded], 17.4 KB
  __shared__ float sBias[64];        // [e*16 + gate*4 + j]

  const int tid = threadIdx.x;
  const int w = tid >> 6;            // wave 0..7 = k-slice
  const int lane = tid & 63;
  const int wg = blockIdx.x;
  const int n16 = lane & 15;
  const int kk0 = w * 6;             // global kstep base (of 48)

  // ---- one-time: gather B fragments into registers (96 VGPRs) ----
  // frag (f=expert, i): B[col = f*16+n16][k = (kk0+i)*32 + (lane>>4)*8 + e]
  s16x8 wr[4][6];
  {
    const int gate = n16 >> 2, j = lane & 3;
    #pragma unroll
    for (int f = 0; f < 4; ++f) {
      const int row = f * G4 + gate * HID + wg * 4 + j;   // W row (output col)
      #pragma unroll
      for (int i = 0; i < 6; ++i) {
        const int kk = kk0 + i;
        const float* src = (kk < 32)
            ? (Whh + (size_t)row * HID + (kk << 5) + ((lane >> 4) << 3))
            : (Wih + (size_t)row * INF + ((kk - 32) << 5) + ((lane >> 4) << 3));
        float4 a = reinterpret_cast<const float4*>(src)[0];
        float4 b = reinterpret_cast<const float4*>(src)[1];
        s16x8 o;
        o[0]=f2bf(a.x); o[1]=f2bf(a.y); o[2]=f2bf(a.z); o[3]=f2bf(a.w);
        o[4]=f2bf(b.x); o[5]=f2bf(b.y); o[6]=f2bf(b.z); o[7]=f2bf(b.w);
        wr[f][i] = o;
      }
    }
  }

  if (tid < 64) {
    const int e = tid >> 4, g = (tid >> 2) & 3, jj = tid & 3;
    const int idx = e * G4 + g * HID + wg * 4 + jj;
    sBias[tid] = bih[idx] + bhh[idx];
  }
  float cpriv = 0.f;
  if (tid < 256) cpriv = c0[(tid >> 2) * HID + wg * 4 + (tid & 3)];
  __syncthreads();

  // stage phase pc (512 k-cols x 64 rows) into buffer buf, XOR-swizzled source.
  auto stage = [&](int buf, int pc, const short* h_in, const short* xrow) {
    #pragma unroll
    for (int rr = 0; rr < 8; ++rr) {
      const int q = tid * 16 + rr * 8192;               // byte offset in buffer
      const int r2 = q >> 10;                           // row 0..63
      const int kb = (q & 1023) ^ ((r2 & 7) << 4);      // logical byte-in-row
      const short* g = (pc < 2)
          ? (h_in + r2 * 1024 + pc * 512 + (kb >> 1))
          : (xrow + r2 * 512 + (kb >> 1));
      short* l = sA + buf * 32768 + ((w * 1024 + rr * 8192) >> 1);
      __builtin_amdgcn_global_load_lds((const __attribute__((address_space(1))) void*)g,
                                       (__attribute__((address_space(3))) void*)l,
                                       16, 0, 0);
    }
  };

  for (int t = 0; t < SEQ; ++t) {
    const short* h_in = hbuf + (t & 1) * (BS * HID);
    const short* xrow = xb + (size_t)t * (BS * INF);

    f32x4 acc[4][4];                                    // [m][expert]
    #pragma unroll
    for (int m = 0; m < 4; ++m)
      #pragma unroll
      for (int f = 0; f < 4; ++f)
        acc[m][f] = (f32x4){0.f, 0.f, 0.f, 0.f};

    stage(0, 0, h_in, xrow);
    __syncthreads();
    stage(1, 1, h_in, xrow);
    PHASE(0, 0)
    __syncthreads();
    stage(0, 2, h_in, xrow);
    PHASE(1, 32768)
    __syncthreads();
    PHASE(2, 0)

    // 8-phase rotation reduction into sG (col-major: sG[n*68 + row]).
    // Unit u = (m>>1)*4 + f handled by wave with (w+p)&7 == u at phase p.
    #pragma unroll
    for (int p = 0; p < 8; ++p) {
      if (p) __syncthreads();
      #pragma unroll
      for (int m = 0; m < 4; ++m) {
        #pragma unroll
        for (int f = 0; f < 4; ++f) {
          if ((((m >> 1) << 2) | f) == ((w + p) & 7)) {
            const int idx = (f * 16 + n16) * 68 + m * 16 + ((lane >> 4) << 2);
            f32x4* ptr = reinterpret_cast<f32x4*>(&sG[idx]);
            if (p == 0) *ptr = acc[m][f];
            else { f32x4 v = *ptr; v += acc[m][f]; *ptr = v; }
          }
        }
      }
    }
    __syncthreads();

    // cell update: thread owns (b, jj)
    if (tid < 256) {
      const int b = tid >> 2, jj = tid & 3;
      const int hcol = wg * 4 + jj;
      const int hidx = b * HID + hcol;
      float hn = 0.f, cn = 0.f;
      #pragma unroll
      for (int e = 0; e < 4; ++e) {
        float iv = sG[(e * 16 +  0 + jj) * 68 + b] + sBias[e * 16 +  0 + jj];
        float fv = sG[(e * 16 +  4 + jj) * 68 + b] + sBias[e * 16 +  4 + jj];
        float gv = sG[(e * 16 +  8 + jj) * 68 + b] + sBias[e * 16 +  8 + jj];
        float ov = sG[(e * 16 + 12 + jj) * 68 + b] + sBias[e * 16 + 12 + jj];
        float is = sigf(iv), fs = sigf(fv), gs = tanhfast(gv), os = sigf(ov);
        float ck = fs * cpriv + is * gs;
        float hk = os * tanhfast(ck);
        float wk = wtsbuf[t * 4 + e];
        hn += wk * hk;
        cn += wk * ck;
      }
      cpriv = cn;
      hbuf[((t + 1) & 1) * (BS * HID) + hidx] = f2bf(hn);
      outf[(size_t)t * (BS * HID) + hidx] = hn;
      if (t == SEQ - 1) {
        outf[(size_t)SEQ * BS * HID + hidx] = hn;              // final h
        outf[(size_t)SEQ * BS * HID + BS * HID + hidx] = cn;   // final c
      }
    }

    // grid barrier (device-scope): release h_out, arrive, spin, acquire.
    if (t < SEQ - 1) {
      __threadfence();
      __syncthreads();
      if (tid == 0) atomicAdd(&bar[(wg & 63) << 4], 1u);
      if (w == 0) {
        const unsigned target = (unsigned)(t + 1) * 4u;
        while (1) {
          unsigned v = __hip_atomic_load(&bar[lane << 4], __ATOMIC_RELAXED,
                                         __HIP_MEMORY_SCOPE_AGENT);
          if (__all((int)(v >= target))) break;
          __builtin_amdgcn_s_sleep(8);
        }
      }
      __syncthreads();
      __threadfence();
    }
  }
}

extern "C" void kernel_launch(void* const* d_in, const int* in_sizes, int n_in,
                              void* d_out, int out_size, void* d_ws, size_t ws_size,
                              hipStream_t stream) {
  const float* x    = (const float*)d_in[0];
  const float* h0   = (const float*)d_in[1];
  const float* c0   = (const float*)d_in[2];
  const float* coef = (const float*)d_in[3];
  const float* Wih  = (const float*)d_in[4];
  const float* Whh  = (const float*)d_in[5];
  const float* bih  = (const float*)d_in[6];
  const float* bhh  = (const float*)d_in[7];
  float* out = (float*)d_out;
  char* ws = (char*)d_ws;

  short*    xb      = (short*)(ws);                  // 16777216 B
  float*    wtsbuf  = (float*)(ws + 16777216);       // 4096 B
  short*    hbuf    = (short*)(ws + 16781312);       // 2 x 131072 B
  unsigned* bar     = (unsigned*)(ws + 17043456);    // 4096 B

  cvt_kernel<<<2048, 256, 0, stream>>>(x, xb, (SEQ * BS * INF) / 4);
  prep_misc<<<256, 256, 0, stream>>>(h0, coef, hbuf, wtsbuf, bar);

  moo_persistent<<<256, 512, 0, stream>>>(Wih, Whh, bih, bhh, c0, xb, wtsbuf,
                                          hbuf, bar, out);
}

// Round 9
// 3575.230 us; speedup vs baseline: 5.5750x; 5.5750x over previous
//
#include <hip/hip_runtime.h>

#define SEQ 256
#define BS 64
#define INF 512
#define HID 1024
#define KEXP 4
#define G4 4096          // 4*HID
#define BH (BS * HID)    // 65536

typedef __attribute__((ext_vector_type(8))) short s16x8;
typedef __attribute__((ext_vector_type(4))) float f32x4;

__device__ __forceinline__ short f2bf(float x) {
  unsigned u = __builtin_bit_cast(unsigned, x);
  u += 0x7fffu + ((u >> 16) & 1u);
  return (short)(u >> 16);
}

__device__ __forceinline__ float sigf(float x) {
  return 1.f / (1.f + __expf(-x));
}
__device__ __forceinline__ float tanhfast(float x) {
  return 2.f / (1.f + __expf(-2.f * x)) - 1.f;
}

__global__ void cvt_kernel(const float* __restrict__ s, short* __restrict__ d, int n4) {
  int stride = gridDim.x * blockDim.x;
  for (int i = blockIdx.x * blockDim.x + threadIdx.x; i < n4; i += stride) {
    float4 v = reinterpret_cast<const float4*>(s)[i];
    short4 o = make_short4(f2bf(v.x), f2bf(v.y), f2bf(v.z), f2bf(v.w));
    reinterpret_cast<short4*>(d)[i] = o;
  }
}

__global__ void prep_misc(const float* __restrict__ h0, const float* __restrict__ coef,
                          short* __restrict__ hseq, float* __restrict__ wtsbuf,
                          unsigned* __restrict__ bar) {
  int i = blockIdx.x * blockDim.x + threadIdx.x;   // 65536 threads == BS*HID
  hseq[i] = f2bf(h0[i]);                           // hseq slab 0 = h0
  if (i < 4096) bar[i] = 0u;
  if (i < SEQ) {
    float a = coef[i*4+0], b = coef[i*4+1], c = coef[i*4+2], d = coef[i*4+3];
    float m = fmaxf(fmaxf(a, b), fmaxf(c, d));
    float ea = __expf(a-m), eb = __expf(b-m), ec = __expf(c-m), ed = __expf(d-m);
    float inv = 1.f / (ea+eb+ec+ed);
    wtsbuf[i*4+0]=ea*inv; wtsbuf[i*4+1]=eb*inv; wtsbuf[i*4+2]=ec*inv; wtsbuf[i*4+3]=ed*inv;
  }
}

// Persistent kernel: 256 WGs x 512 threads, 1 WG/CU (148KB LDS forces it).
// WG wg owns h-cols [wg*4, wg*4+4) => 64 GEMM N-cols (4 experts x 4 gates x 4 j).
// Wave w (0..7) owns k-slice [w*192,+192) with B (weights) in VGPRs (24 frags).
// h state: rotating per-step slabs hseq[t] (no address reuse => no stale L2
// lines => no fences; kernel-start implicit acquire invalidates poison lines).
// h written with agent-scope atomic stores (route to coherence point / L3).
// Grid barrier: 16 leaf counters + root + broadcast gen word; tid0-only,
// single-lane relaxed poll with s_sleep.
#define PHASE(c, bufofs)                                                         \
  { _Pragma("unroll")                                                            \
    for (int i = 0; i < 6; ++i) {                                                \
      if (((kk0 + i) >> 4) == (c)) {                                             \
        const int kbyte = ((kk0 + i - (c) * 16) << 6) + ((lane >> 4) << 4);      \
        _Pragma("unroll")                                                        \
        for (int m = 0; m < 4; ++m) {                                            \
          const int rowA = m * 16 + n16;                                         \
          const int addr = rowA * 1024 + (kbyte ^ ((rowA & 7) << 4));            \
          s16x8 af = *reinterpret_cast<const s16x8*>(sA + (bufofs) + (addr >> 1)); \
          acc[m][0] = __builtin_amdgcn_mfma_f32_16x16x32_bf16(af, wr[0][i], acc[m][0], 0, 0, 0); \
          acc[m][1] = __builtin_amdgcn_mfma_f32_16x16x32_bf16(af, wr[1][i], acc[m][1], 0, 0, 0); \
          acc[m][2] = __builtin_amdgcn_mfma_f32_16x16x32_bf16(af, wr[2][i], acc[m][2], 0, 0, 0); \
          acc[m][3] = __builtin_amdgcn_mfma_f32_16x16x32_bf16(af, wr[3][i], acc[m][3], 0, 0, 0); \
        }                                                                        \
      }                                                                          \
    }                                                                            \
  }

__global__ __launch_bounds__(512, 1) void moo_persistent(
    const float* __restrict__ Wih,   // [K][4096][512] f32
    const float* __restrict__ Whh,   // [K][4096][1024] f32
    const float* __restrict__ bih,   // [K][4096]
    const float* __restrict__ bhh,   // [K][4096]
    const float* __restrict__ c0,    // [64][1024]
    const short* __restrict__ xb,    // [SEQ][64][512] bf16
    const float* __restrict__ wtsbuf,// [SEQ][4]
    short* __restrict__ hseq,        // [SEQ+1][64][1024] bf16 rotating slabs
    unsigned* __restrict__ bar,      // [4096]: leaves @ i*64 (i<16), root @1024, gen @1040
    float* __restrict__ outf)        // d_out
{
  __shared__ short sA[65536];        // 2 x [64 rows][512 k] bf16 = 128 KB
  __shared__ float sG[64 * 68];      // col-major gate grid [n][row-padded], 17.4 KB
  __shared__ float sBias[64];        // [e*16 + gate*4 + j]

  const int tid = threadIdx.x;
  const int w = tid >> 6;            // wave 0..7 = k-slice
  const int lane = tid & 63;
  const int wg = blockIdx.x;
  const int n16 = lane & 15;
  const int kk0 = w * 6;             // global kstep base (of 48)

  // ---- one-time: gather B fragments into registers (96 VGPRs) ----
  s16x8 wr[4][6];
  {
    const int gate = n16 >> 2, j = lane & 3;
    #pragma unroll
    for (int f = 0; f < 4; ++f) {
      const int row = f * G4 + gate * HID + wg * 4 + j;   // W row (output col)
      #pragma unroll
      for (int i = 0; i < 6; ++i) {
        const int kk = kk0 + i;
        const float* src = (kk < 32)
            ? (Whh + (size_t)row * HID + (kk << 5) + ((lane >> 4) << 3))
            : (Wih + (size_t)row * INF + ((kk - 32) << 5) + ((lane >> 4) << 3));
        float4 a = reinterpret_cast<const float4*>(src)[0];
        float4 b = reinterpret_cast<const float4*>(src)[1];
        s16x8 o;
        o[0]=f2bf(a.x); o[1]=f2bf(a.y); o[2]=f2bf(a.z); o[3]=f2bf(a.w);
        o[4]=f2bf(b.x); o[5]=f2bf(b.y); o[6]=f2bf(b.z); o[7]=f2bf(b.w);
        wr[f][i] = o;
      }
    }
  }

  if (tid < 64) {
    const int e = tid >> 4, g = (tid >> 2) & 3, jj = tid & 3;
    const int idx = e * G4 + g * HID + wg * 4 + jj;
    sBias[tid] = bih[idx] + bhh[idx];
  }
  float cpriv[2] = {0.f, 0.f};
  if (tid < 128) {
    const int b = tid >> 1, p = (tid & 1) << 1;
    cpriv[0] = c0[b * HID + wg * 4 + p];
    cpriv[1] = c0[b * HID + wg * 4 + p + 1];
  }
  __syncthreads();

  // stage phase pc (512 k-cols x 64 rows) into buffer buf, XOR-swizzled source.
  auto stage = [&](int buf, int pc, const short* h_in, const short* xrow) {
    #pragma unroll
    for (int rr = 0; rr < 8; ++rr) {
      const int q = tid * 16 + rr * 8192;               // byte offset in buffer
      const int r2 = q >> 10;                           // row 0..63
      const int kb = (q & 1023) ^ ((r2 & 7) << 4);      // logical byte-in-row
      const short* g = (pc < 2)
          ? (h_in + r2 * 1024 + pc * 512 + (kb >> 1))
          : (xrow + r2 * 512 + (kb >> 1));
      short* l = sA + buf * 32768 + ((w * 1024 + rr * 8192) >> 1);
      __builtin_amdgcn_global_load_lds((const __attribute__((address_space(1))) void*)g,
                                       (__attribute__((address_space(3))) void*)l,
                                       16, 0, 0);
    }
  };

  for (int t = 0; t < SEQ; ++t) {
    const short* h_in = hseq + (size_t)t * BH;
    const short* xrow = xb + (size_t)t * (BS * INF);

    f32x4 acc[4][4];                                    // [m][expert]
    #pragma unroll
    for (int m = 0; m < 4; ++m)
      #pragma unroll
      for (int f = 0; f < 4; ++f)
        acc[m][f] = (f32x4){0.f, 0.f, 0.f, 0.f};

    stage(0, 0, h_in, xrow);
    __syncthreads();
    stage(1, 1, h_in, xrow);
    PHASE(0, 0)
    __syncthreads();
    stage(0, 2, h_in, xrow);
    PHASE(1, 32768)
    __syncthreads();
    PHASE(2, 0)

    // 8-phase rotation reduction into sG (col-major: sG[n*68 + row]).
    #pragma unroll
    for (int p = 0; p < 8; ++p) {
      if (p) __syncthreads();
      #pragma unroll
      for (int m = 0; m < 4; ++m) {
        #pragma unroll
        for (int f = 0; f < 4; ++f) {
          if ((((m >> 1) << 2) | f) == ((w + p) & 7)) {
            const int idx = (f * 16 + n16) * 68 + m * 16 + ((lane >> 4) << 2);
            f32x4* ptr = reinterpret_cast<f32x4*>(&sG[idx]);
            if (p == 0) *ptr = acc[m][f];
            else { f32x4 v = *ptr; v += acc[m][f]; *ptr = v; }
          }
        }
      }
    }
    __syncthreads();

    // cell update: thread owns (b, p..p+1); h -> next slab via agent store.
    if (tid < 128) {
      const int b = tid >> 1, p = (tid & 1) << 1;
      const int col = wg * 4 + p;
      float hnv[2], cnv[2];
      #pragma unroll
      for (int q = 0; q < 2; ++q) {
        const int jj = p + q;
        float hn = 0.f, cn = 0.f;
        #pragma unroll
        for (int e = 0; e < 4; ++e) {
          float iv = sG[(e * 16 +  0 + jj) * 68 + b] + sBias[e * 16 +  0 + jj];
          float fv = sG[(e * 16 +  4 + jj) * 68 + b] + sBias[e * 16 +  4 + jj];
          float gv = sG[(e * 16 +  8 + jj) * 68 + b] + sBias[e * 16 +  8 + jj];
          float ov = sG[(e * 16 + 12 + jj) * 68 + b] + sBias[e * 16 + 12 + jj];
          float is = sigf(iv), fs = sigf(fv), gs = tanhfast(gv), os = sigf(ov);
          float ck = fs * cpriv[q] + is * gs;
          float hk = os * tanhfast(ck);
          float wk = wtsbuf[t * 4 + e];
          hn += wk * hk;
          cn += wk * ck;
        }
        hnv[q] = hn; cnv[q] = cn; cpriv[q] = cn;
      }
      unsigned hv = (unsigned)(unsigned short)f2bf(hnv[0]) |
                    ((unsigned)(unsigned short)f2bf(hnv[1]) << 16);
      unsigned* hnext = (unsigned*)(hseq + (size_t)(t + 1) * BH);
      __hip_atomic_store(hnext + ((b * HID + col) >> 1), hv,
                         __ATOMIC_RELAXED, __HIP_MEMORY_SCOPE_AGENT);
      float2 ov2 = make_float2(hnv[0], hnv[1]);
      *reinterpret_cast<float2*>(outf + (size_t)t * BH + b * HID + col) = ov2;
      if (t == SEQ - 1) {
        *reinterpret_cast<float2*>(outf + (size_t)SEQ * BH + b * HID + col) = ov2;
        *reinterpret_cast<float2*>(outf + (size_t)SEQ * BH + BH + b * HID + col) =
            make_float2(cnv[0], cnv[1]);
      }
    }

    // grid barrier: tree arrival + single-lane broadcast poll. No fences
    // (rotating h slabs => no stale lines; agent stores reach L3; syncthreads
    // drains vmcnt before arrival).
    if (t < SEQ - 1) {
      __syncthreads();
      if (tid == 0) {
        const unsigned tgt = 16u * (unsigned)(t + 1);
        unsigned old = atomicAdd(&bar[(wg >> 4) * 64], 1u);
        if (old == tgt - 1u) {
          unsigned old2 = atomicAdd(&bar[1024], 1u);
          if (old2 == tgt - 1u)
            __hip_atomic_store(&bar[1040], (unsigned)(t + 1),
                               __ATOMIC_RELAXED, __HIP_MEMORY_SCOPE_AGENT);
        }
        while (__hip_atomic_load(&bar[1040], __ATOMIC_RELAXED,
                                 __HIP_MEMORY_SCOPE_AGENT) < (unsigned)(t + 1))
          __builtin_amdgcn_s_sleep(2);
      }
      __syncthreads();
    }
  }
}

extern "C" void kernel_launch(void* const* d_in, const int* in_sizes, int n_in,
                              void* d_out, int out_size, void* d_ws, size_t ws_size,
                              hipStream_t stream) {
  const float* x    = (const float*)d_in[0];
  const float* h0   = (const float*)d_in[1];
  const float* c0   = (const float*)d_in[2];
  const float* coef = (const float*)d_in[3];
  const float* Wih  = (const float*)d_in[4];
  const float* Whh  = (const float*)d_in[5];
  const float* bih  = (const float*)d_in[6];
  const float* bhh  = (const float*)d_in[7];
  float* out = (float*)d_out;
  char* ws = (char*)d_ws;

  short*    xb      = (short*)(ws);                  // 16777216 B
  float*    wtsbuf  = (float*)(ws + 16777216);       // 4096 B
  unsigned* bar     = (unsigned*)(ws + 16781312);    // 16384 B
  short*    hseq    = (short*)(ws + 16797696);       // 257 x 131072 B = 33685504 B

  cvt_kernel<<<2048, 256, 0, stream>>>(x, xb, (SEQ * BS * INF) / 4);
  prep_misc<<<256, 256, 0, stream>>>(h0, coef, hseq, wtsbuf, bar);

  moo_persistent<<<256, 512, 0, stream>>>(Wih, Whh, bih, bhh, c0, xb, wtsbuf,
                                          hseq, bar, out);
}

// Round 11
// 3021.739 us; speedup vs baseline: 6.5962x; 1.1832x over previous
//
#include <hip/hip_runtime.h>

#define SEQ 256
#define BS 64
#define INF 512
#define HID 1024
#define KEXP 4
#define G4 4096          // 4*HID
#define BH (BS * HID)    // 65536

typedef __attribute__((ext_vector_type(8))) short s16x8;
typedef __attribute__((ext_vector_type(4))) float f32x4;
typedef __attribute__((ext_vector_type(2))) float f32x2;

__device__ __forceinline__ short f2bf(float x) {
  unsigned u = __builtin_bit_cast(unsigned, x);
  u += 0x7fffu + ((u >> 16) & 1u);
  return (short)(u >> 16);
}

__device__ __forceinline__ float sigf(float x) {
  return 1.f / (1.f + __expf(-x));
}
__device__ __forceinline__ float tanhfast(float x) {
  return 2.f / (1.f + __expf(-2.f * x)) - 1.f;
}

__global__ void cvt_kernel(const float* __restrict__ s, short* __restrict__ d, int n4) {
  int stride = gridDim.x * blockDim.x;
  for (int i = blockIdx.x * blockDim.x + threadIdx.x; i < n4; i += stride) {
    float4 v = reinterpret_cast<const float4*>(s)[i];
    short4 o = make_short4(f2bf(v.x), f2bf(v.y), f2bf(v.z), f2bf(v.w));
    reinterpret_cast<short4*>(d)[i] = o;
  }
}

__global__ void prep_misc(const float* __restrict__ h0, const float* __restrict__ coef,
                          short* __restrict__ hseq, float* __restrict__ wtsbuf,
                          unsigned* __restrict__ bar) {
  int i = blockIdx.x * blockDim.x + threadIdx.x;   // 65536 threads == BS*HID
  hseq[i] = f2bf(h0[i]);                           // hseq slab 0 = h0
  if (i < 4096) bar[i] = 0u;
  if (i < SEQ) {
    float a = coef[i*4+0], b = coef[i*4+1], c = coef[i*4+2], d = coef[i*4+3];
    float m = fmaxf(fmaxf(a, b), fmaxf(c, d));
    float ea = __expf(a-m), eb = __expf(b-m), ec = __expf(c-m), ed = __expf(d-m);
    float inv = 1.f / (ea+eb+ec+ed);
    wtsbuf[i*4+0]=ea*inv; wtsbuf[i*4+1]=eb*inv; wtsbuf[i*4+2]=ec*inv; wtsbuf[i*4+3]=ed*inv;
  }
}

// Persistent kernel: 256 WGs x 512 threads, 1 WG/CU (153KB LDS forces it).
// WG wg owns h-cols [wg*4, wg*4+4) => 64 GEMM N-cols (4 experts x 4 gates x 4 j).
// Wave w (0..7) owns k-slice [w*192,+192) with B (weights) in VGPRs (24 frags).
// Pipeline per step: [x(t) pre-staged before t's barrier] -> compute x-part
// while h0 stages -> compute h0 while h1 stages -> compute h1 -> prefetch
// x(t+1) -> LDS k-reduction -> cell -> barrier (x-prefetch + store drain
// overlap the wait). Grid barrier: 16 leaves + root + 8 per-XCD gen copies.
#define PHASE(c, bufofs)                                                         \
  { _Pragma("unroll")                                                            \
    for (int i = 0; i < 6; ++i) {                                                \
      if (((kk0 + i) >> 4) == (c)) {                                             \
        const int kbyte = ((kk0 + i - (c) * 16) << 6) + ((lane >> 4) << 4);      \
        _Pragma("unroll")                                                        \
        for (int m = 0; m < 4; ++m) {                                            \
          const int rowA = m * 16 + n16;                                         \
          const int addr = rowA * 1024 + (kbyte ^ ((rowA & 7) << 4));            \
          s16x8 af = *reinterpret_cast<const s16x8*>(sA + (bufofs) + (addr >> 1)); \
          acc[m][0] = __builtin_amdgcn_mfma_f32_16x16x32_bf16(af, wr[0][i], acc[m][0], 0, 0, 0); \
          acc[m][1] = __builtin_amdgcn_mfma_f32_16x16x32_bf16(af, wr[1][i], acc[m][1], 0, 0, 0); \
          acc[m][2] = __builtin_amdgcn_mfma_f32_16x16x32_bf16(af, wr[2][i], acc[m][2], 0, 0, 0); \
          acc[m][3] = __builtin_amdgcn_mfma_f32_16x16x32_bf16(af, wr[3][i], acc[m][3], 0, 0, 0); \
        }                                                                        \
      }                                                                          \
    }                                                                            \
  }

__global__ __launch_bounds__(512, 2) void moo_persistent(
    const float* __restrict__ Wih,   // [K][4096][512] f32
    const float* __restrict__ Whh,   // [K][4096][1024] f32
    const float* __restrict__ bih,   // [K][4096]
    const float* __restrict__ bhh,   // [K][4096]
    const float* __restrict__ c0,    // [64][1024]
    const short* __restrict__ xb,    // [SEQ][64][512] bf16
    const float* __restrict__ wtsbuf,// [SEQ][4]
    short* __restrict__ hseq,        // [SEQ+1][64][1024] bf16 rotating slabs
    unsigned* __restrict__ bar,      // [4096]: leaves @ i*64 (i<16), root @1024, gen @1280+x*16
    float* __restrict__ outf)        // d_out
{
  __shared__ short sA[65536];        // 2 x [64 rows][512 k] bf16 = 128 KB
  __shared__ float sG[64 * 68];      // col-major gate grid [n][row-padded], 17.4 KB
  __shared__ float sBias[64];        // [e*16 + gate*4 + j]
  __shared__ float sWts[SEQ * 4];    // softmax weights, 4 KB

  const int tid = threadIdx.x;
  const int w = tid >> 6;            // wave 0..7 = k-slice
  const int lane = tid & 63;
  const int wg = blockIdx.x;
  const int n16 = lane & 15;
  const int kk0 = w * 6;             // global kstep base (of 48)

  // ---- one-time: gather B fragments into registers (96 VGPRs), NT loads ----
  s16x8 wr[4][6];
  {
    const int gate = n16 >> 2, j = lane & 3;
    #pragma unroll
    for (int f = 0; f < 4; ++f) {
      const int row = f * G4 + gate * HID + wg * 4 + j;   // W row (output col)
      #pragma unroll
      for (int i = 0; i < 6; ++i) {
        const int kk = kk0 + i;
        const float* src = (kk < 32)
            ? (Whh + (size_t)row * HID + (kk << 5) + ((lane >> 4) << 3))
            : (Wih + (size_t)row * INF + ((kk - 32) << 5) + ((lane >> 4) << 3));
        f32x4 a = __builtin_nontemporal_load(reinterpret_cast<const f32x4*>(src));
        f32x4 b = __builtin_nontemporal_load(reinterpret_cast<const f32x4*>(src + 4));
        s16x8 o;
        o[0]=f2bf(a[0]); o[1]=f2bf(a[1]); o[2]=f2bf(a[2]); o[3]=f2bf(a[3]);
        o[4]=f2bf(b[0]); o[5]=f2bf(b[1]); o[6]=f2bf(b[2]); o[7]=f2bf(b[3]);
        wr[f][i] = o;
      }
    }
  }

  if (tid < 64) {
    const int e = tid >> 4, g = (tid >> 2) & 3, jj = tid & 3;
    const int idx = e * G4 + g * HID + wg * 4 + jj;
    sBias[tid] = bih[idx] + bhh[idx];
  }
  sWts[tid] = wtsbuf[tid];
  sWts[tid + 512] = wtsbuf[tid + 512];
  float cpriv[2] = {0.f, 0.f};
  if (tid < 128) {
    const int b = tid >> 1, p = (tid & 1) << 1;
    cpriv[0] = c0[b * HID + wg * 4 + p];
    cpriv[1] = c0[b * HID + wg * 4 + p + 1];
  }

  // stage 512 k-cols x 64 rows into sA+bufofs from g0 (row stride rs shorts),
  // XOR-swizzled source (linear LDS dest; PHASE read applies same XOR).
  auto stage = [&](int bufofs, const short* g0, int rs) {
    #pragma unroll
    for (int rr = 0; rr < 8; ++rr) {
      const int q = tid * 16 + rr * 8192;               // byte offset in buffer
      const int r2 = q >> 10;                           // row 0..63
      const int kb = (q & 1023) ^ ((r2 & 7) << 4);      // logical byte-in-row
      const short* g = g0 + r2 * rs + (kb >> 1);
      short* l = sA + bufofs + ((w * 1024 + rr * 8192) >> 1);
      __builtin_amdgcn_global_load_lds((const __attribute__((address_space(1))) void*)g,
                                       (__attribute__((address_space(3))) void*)l,
                                       16, 0, 0);
    }
  };

  // prologue: x(0) into buf0
  stage(0, xb, 512);
  __syncthreads();

  for (int t = 0; t < SEQ; ++t) {
    const short* h_in = hseq + (size_t)t * BH;
    const int XO = (t & 1) * 32768;                     // buffer holding x(t)
    const int OO = XO ^ 32768;

    f32x4 acc[4][4];                                    // [m][expert]
    #pragma unroll
    for (int m = 0; m < 4; ++m)
      #pragma unroll
      for (int f = 0; f < 4; ++f)
        acc[m][f] = (f32x4){0.f, 0.f, 0.f, 0.f};

    stage(OO, h_in, 1024);                              // h cols 0-511
    PHASE(2, XO)                                        // x-part (pre-staged)
    __syncthreads();
    stage(XO, h_in + 512, 1024);                        // h cols 512-1023
    PHASE(0, OO)                                        // h0-part
    __syncthreads();
    PHASE(1, XO)                                        // h1-part
    if (t + 1 < SEQ)                                    // prefetch x(t+1):
      stage(OO, xb + (size_t)(t + 1) * (BS * INF), 512);// overlaps reduce+barrier

    // 8-phase rotation reduction into sG (col-major: sG[n*68 + row]).
    #pragma unroll
    for (int p = 0; p < 8; ++p) {
      if (p) __syncthreads();
      #pragma unroll
      for (int m = 0; m < 4; ++m) {
        #pragma unroll
        for (int f = 0; f < 4; ++f) {
          if ((((m >> 1) << 2) | f) == ((w + p) & 7)) {
            const int idx = (f * 16 + n16) * 68 + m * 16 + ((lane >> 4) << 2);
            f32x4* ptr = reinterpret_cast<f32x4*>(&sG[idx]);
            if (p == 0) *ptr = acc[m][f];
            else { f32x4 v = *ptr; v += acc[m][f]; *ptr = v; }
          }
        }
      }
    }
    __syncthreads();

    // cell update: thread owns (b, p..p+1); h -> next slab via agent store;
    // d_out via nontemporal stores (no write-allocate RMW).
    if (tid < 128) {
      const int b = tid >> 1, p = (tid & 1) << 1;
      const int col = wg * 4 + p;
      float hnv[2], cnv[2];
      #pragma unroll
      for (int q = 0; q < 2; ++q) {
        const int jj = p + q;
        float hn = 0.f, cn = 0.f;
        #pragma unroll
        for (int e = 0; e < 4; ++e) {
          float iv = sG[(e * 16 +  0 + jj) * 68 + b] + sBias[e * 16 +  0 + jj];
          float fv = sG[(e * 16 +  4 + jj) * 68 + b] + sBias[e * 16 +  4 + jj];
          float gv = sG[(e * 16 +  8 + jj) * 68 + b] + sBias[e * 16 +  8 + jj];
          float ov = sG[(e * 16 + 12 + jj) * 68 + b] + sBias[e * 16 + 12 + jj];
          float is = sigf(iv), fs = sigf(fv), gs = tanhfast(gv), os = sigf(ov);
          float ck = fs * cpriv[q] + is * gs;
          float hk = os * tanhfast(ck);
          float wk = sWts[t * 4 + e];
          hn += wk * hk;
          cn += wk * ck;
        }
        hnv[q] = hn; cnv[q] = cn; cpriv[q] = cn;
      }
      unsigned hv = (unsigned)(unsigned short)f2bf(hnv[0]) |
                    ((unsigned)(unsigned short)f2bf(hnv[1]) << 16);
      unsigned* hnext = (unsigned*)(hseq + (size_t)(t + 1) * BH);
      __hip_atomic_store(hnext + ((b * HID + col) >> 1), hv,
                         __ATOMIC_RELAXED, __HIP_MEMORY_SCOPE_AGENT);
      f32x2 ov2 = {hnv[0], hnv[1]};
      __builtin_nontemporal_store(ov2,
          reinterpret_cast<f32x2*>(outf + (size_t)t * BH + b * HID + col));
      if (t == SEQ - 1) {
        f32x2 cv2 = {cnv[0], cnv[1]};
        __builtin_nontemporal_store(ov2,
            reinterpret_cast<f32x2*>(outf + (size_t)SEQ * BH + b * HID + col));
        __builtin_nontemporal_store(cv2,
            reinterpret_cast<f32x2*>(outf + (size_t)SEQ * BH + BH + b * HID + col));
      }
    }

    // grid barrier: tree arrival + per-XCD gen broadcast (8 copies).
    if (t < SEQ - 1) {
      __syncthreads();                                  // drains stores + x-prefetch
      if (tid == 0) {
        const unsigned tgt = 16u * (unsigned)(t + 1);
        unsigned old = atomicAdd(&bar[(wg >> 4) * 64], 1u);
        if (old == tgt - 1u) {
          unsigned old2 = atomicAdd(&bar[1024], 1u);
          if (old2 == tgt - 1u) {
            #pragma unroll
            for (int xg = 0; xg < 8; ++xg)
              __hip_atomic_store(&bar[1280 + xg * 16], (unsigned)(t + 1),
                                 __ATOMIC_RELAXED, __HIP_MEMORY_SCOPE_AGENT);
          }
        }
        while (__hip_atomic_load(&bar[1280 + (wg & 7) * 16], __ATOMIC_RELAXED,
                                 __HIP_MEMORY_SCOPE_AGENT) < (unsigned)(t + 1))
          __builtin_amdgcn_s_sleep(2);
      }
      __syncthreads();
    }
  }
}

extern "C" void kernel_launch(void* const* d_in, const int* in_sizes, int n_in,
                              void* d_out, int out_size, void* d_ws, size_t ws_size,
                              hipStream_t stream) {
  const float* x    = (const float*)d_in[0];
  const float* h0   = (const float*)d_in[1];
  const float* c0   = (const float*)d_in[2];
  const float* coef = (const float*)d_in[3];
  const float* Wih  = (const float*)d_in[4];
  const float* Whh  = (const float*)d_in[5];
  const float* bih  = (const float*)d_in[6];
  const float* bhh  = (const float*)d_in[7];
  float* out = (float*)d_out;
  char* ws = (char*)d_ws;

  short*    xb      = (short*)(ws);                  // 16777216 B
  float*    wtsbuf  = (float*)(ws + 16777216);       // 4096 B
  unsigned* bar     = (unsigned*)(ws + 16781312);    // 16384 B
  short*    hseq    = (short*)(ws + 16797696);       // 257 x 131072 B = 33685504 B

  cvt_kernel<<<2048, 256, 0, stream>>>(x, xb, (SEQ * BS * INF) / 4);
  prep_misc<<<256, 256, 0, stream>>>(h0, coef, hseq, wtsbuf, bar);

  moo_persistent<<<256, 512, 0, stream>>>(Wih, Whh, bih, bhh, c0, xb, wtsbuf,
                                          hseq, bar, out);
}